// Round 1
// baseline (116.034 us; speedup 1.0000x reference)
//
#include <hip/hip_runtime.h>

#define NA 128   // agents per batch
#define ND 32    // obs dim
#define NH 128   // hidden dim
#define NK 16    // neighbours

// 4 rows of W (w0..w3 are float4 over 4 consecutive f) times xv (4 k-values) into ACC (4 f)
#define FMA16(ACC, XV, W0_, W1_, W2_, W3_)                                 \
    ACC.x = fmaf(XV.x, W0_.x, ACC.x); ACC.x = fmaf(XV.y, W1_.x, ACC.x);    \
    ACC.x = fmaf(XV.z, W2_.x, ACC.x); ACC.x = fmaf(XV.w, W3_.x, ACC.x);    \
    ACC.y = fmaf(XV.x, W0_.y, ACC.y); ACC.y = fmaf(XV.y, W1_.y, ACC.y);    \
    ACC.y = fmaf(XV.z, W2_.y, ACC.y); ACC.y = fmaf(XV.w, W3_.y, ACC.y);    \
    ACC.z = fmaf(XV.x, W0_.z, ACC.z); ACC.z = fmaf(XV.y, W1_.z, ACC.z);    \
    ACC.z = fmaf(XV.z, W2_.z, ACC.z); ACC.z = fmaf(XV.w, W3_.z, ACC.z);    \
    ACC.w = fmaf(XV.x, W0_.w, ACC.w); ACC.w = fmaf(XV.y, W1_.w, ACC.w);    \
    ACC.w = fmaf(XV.z, W2_.w, ACC.w); ACC.w = fmaf(XV.w, W3_.w, ACC.w);

// Aggregation: out[j][f] = tanh( d[j] * ( sum_{i in col(j)} g[i][f] + g[j][f] ) + bias[f] )
// Task layout: 1024 tasks = 128 j x 8 lane-chunks; lane-chunk c owns f = c*4 + q*32 + r
// (this partition makes the 8 same-j lanes cover all 32 LDS banks per read -> conflict-free).
__device__ __forceinline__ void agg_layer(int t, const float* __restrict__ g,
                                          float* __restrict__ dst,
                                          const unsigned int (*__restrict__ cm)[4],
                                          const float* __restrict__ dinv,
                                          const float* __restrict__ bias)
{
    #pragma unroll
    for (int rep = 0; rep < 2; ++rep) {
        const int task = t + rep * 512;
        const int j = task >> 3;
        const int off = (task & 7) * 4;
        const float* gj = g + j * 132 + off;
        float4 a0 = *(const float4*)(gj + 0);     // self term (g[j]); d[j]^2 h[j] = d[j]*g[j]
        float4 a1 = *(const float4*)(gj + 32);
        float4 a2 = *(const float4*)(gj + 64);
        float4 a3 = *(const float4*)(gj + 96);
        const uint4 m4 = *(const uint4*)&cm[j][0];
        #pragma unroll
        for (int w = 0; w < 4; ++w) {
            unsigned int m = (w == 0) ? m4.x : (w == 1) ? m4.y : (w == 2) ? m4.z : m4.w;
            while (m) {
                const int bb = __ffs(m) - 1;
                m &= m - 1;
                const float* gi = g + (w * 32 + bb) * 132 + off;
                float4 v;
                v = *(const float4*)(gi + 0);  a0.x += v.x; a0.y += v.y; a0.z += v.z; a0.w += v.w;
                v = *(const float4*)(gi + 32); a1.x += v.x; a1.y += v.y; a1.z += v.z; a1.w += v.w;
                v = *(const float4*)(gi + 64); a2.x += v.x; a2.y += v.y; a2.z += v.z; a2.w += v.w;
                v = *(const float4*)(gi + 96); a3.x += v.x; a3.y += v.y; a3.z += v.z; a3.w += v.w;
            }
        }
        const float dj = dinv[j];
        const float* bs = bias + off;
        float* o = dst + j * 132 + off;
        float4 r;
        r.x = tanhf(fmaf(dj, a0.x, bs[0]));
        r.y = tanhf(fmaf(dj, a0.y, bs[1]));
        r.z = tanhf(fmaf(dj, a0.z, bs[2]));
        r.w = tanhf(fmaf(dj, a0.w, bs[3]));
        *(float4*)(o + 0) = r;
        r.x = tanhf(fmaf(dj, a1.x, bs[32]));
        r.y = tanhf(fmaf(dj, a1.y, bs[33]));
        r.z = tanhf(fmaf(dj, a1.z, bs[34]));
        r.w = tanhf(fmaf(dj, a1.w, bs[35]));
        *(float4*)(o + 32) = r;
        r.x = tanhf(fmaf(dj, a2.x, bs[64]));
        r.y = tanhf(fmaf(dj, a2.y, bs[65]));
        r.z = tanhf(fmaf(dj, a2.z, bs[66]));
        r.w = tanhf(fmaf(dj, a2.w, bs[67]));
        *(float4*)(o + 64) = r;
        r.x = tanhf(fmaf(dj, a3.x, bs[96]));
        r.y = tanhf(fmaf(dj, a3.y, bs[97]));
        r.z = tanhf(fmaf(dj, a3.z, bs[98]));
        r.w = tanhf(fmaf(dj, a3.w, bs[99]));
        *(float4*)(o + 96) = r;
    }
}

__global__ __launch_bounds__(512, 1) void gnn_fused(
    const float* __restrict__ obs,
    const float* __restrict__ W1g, const float* __restrict__ b1g,
    const float* __restrict__ W2g, const float* __restrict__ b2g,
    const float* __restrict__ Wog, const float* __restrict__ bog,
    float* __restrict__ outg)
{
    __shared__ __align__(16) float xl[NA * ND];          // 16 KB: obs tile, later W2 k-panel
    __shared__ float posx[NA], posy[NA];
    __shared__ float dinv[NA];
    __shared__ __align__(16) unsigned int colmask[NA][4]; // col(j) bitmask: bit i set if j in knn(i)
    __shared__ int indeg[NA];
    __shared__ __align__(16) float bias1[NH], bias2[NH], wo[NH];
    __shared__ __align__(16) float buf1[NA * 132];        // dist(129-stride) -> g1 -> g2
    __shared__ __align__(16) float buf2[NA * 132];        // x2 -> x3

    const int t = threadIdx.x;
    const int b = blockIdx.x;

    // ---- stage obs tile + small params ----
    {
        const float4* src = (const float4*)(obs + (size_t)b * NA * ND);
        float4* dst = (float4*)xl;
        dst[t]       = src[t];
        dst[t + 512] = src[t + 512];
    }
    if (t < NA) { indeg[t] = 0; bias1[t] = b1g[t]; bias2[t] = b2g[t]; wo[t] = Wog[t]; }
    ((unsigned int*)colmask)[t] = 0u;   // 512 words exactly
    __syncthreads();
    if (t < NA) { posx[t] = xl[t * ND + 0]; posy[t] = xl[t * ND + 1]; }
    __syncthreads();

    const int i4 = t >> 2;   // agent (knn phases / final dot)
    const int p4 = t & 3;    // 4-lane part

    // ---- pairwise distances, bit-exact vs ref: rn mul/add (no contraction) + rn sqrt ----
    {
        const float xi = posx[i4], yi = posy[i4];
        const int base = i4 * 129 + p4 * 32;
        #pragma unroll
        for (int jj = 0; jj < 32; ++jj) {
            const int j = p4 * 32 + jj;
            const float dx = __fsub_rn(xi, posx[j]);
            const float dy = __fsub_rn(yi, posy[j]);
            const float dsq = __fadd_rn(__fmul_rn(dx, dx), __fmul_rn(dy, dy));
            buf1[base + jj] = __fsqrt_rn(dsq);
        }
    }
    __syncthreads();

    // ---- kNN: 17 lexicographic-(dist,idx) min extractions == top_k(-d,17) incl. tie-break ----
    {
        const int base = i4 * 129 + p4 * 32;
        for (int pass = 0; pass <= NK; ++pass) {
            float bd = __builtin_inff();
            int bj = 0;
            #pragma unroll
            for (int jj = 0; jj < 32; ++jj) {
                const float d = buf1[base + jj];
                const bool lt = d < bd;        // strict < keeps earliest (smallest j) on ties
                bd = lt ? d : bd;
                bj = lt ? jj : bj;
            }
            bj += p4 * 32;
            #pragma unroll
            for (int m = 1; m <= 2; m <<= 1) {
                const float od = __shfl_xor(bd, m, 64);
                const int   oj = __shfl_xor(bj, m, 64);
                const bool take = (od < bd) || ((od == bd) && (oj < bj));
                bd = take ? od : bd;
                bj = take ? oj : bj;
            }
            if ((bj >> 5) == p4) buf1[i4 * 129 + bj] = __builtin_inff();  // owner invalidates
            if (p4 == 0 && pass > 0) {   // pass 0 = self (dist 0), excluded like knn_idx[...,1:]
                atomicOr(&colmask[bj][i4 >> 5], 1u << (i4 & 31));
                atomicAdd(&indeg[bj], 1);
            }
        }
    }
    __syncthreads();
    if (t < NA) dinv[t] = rsqrtf((float)(1 + indeg[t]));
    __syncthreads();

    const int fb = (t & 31) * 4;   // 4 consecutive f per thread
    const int ig = t >> 5;         // 16 groups x 8 rows

    // ---- conv1: g1[i][f] = d[i] * (x @ W1)[i][f]  (K=32, x in xl) ----
    {
        float4 acc[8];
        #pragma unroll
        for (int i = 0; i < 8; ++i) acc[i] = make_float4(0.f, 0.f, 0.f, 0.f);
        #pragma unroll
        for (int ks = 0; ks < ND / 4; ++ks) {
            const float4 w0 = *(const float4*)&W1g[(4 * ks + 0) * NH + fb];
            const float4 w1 = *(const float4*)&W1g[(4 * ks + 1) * NH + fb];
            const float4 w2 = *(const float4*)&W1g[(4 * ks + 2) * NH + fb];
            const float4 w3 = *(const float4*)&W1g[(4 * ks + 3) * NH + fb];
            #pragma unroll
            for (int i = 0; i < 8; ++i) {
                const float4 xv = *(const float4*)&xl[(ig * 8 + i) * ND + ks * 4];
                FMA16(acc[i], xv, w0, w1, w2, w3)
            }
        }
        #pragma unroll
        for (int i = 0; i < 8; ++i) {
            const int ii = ig * 8 + i;
            const float d = dinv[ii];
            float4 r; r.x = d * acc[i].x; r.y = d * acc[i].y; r.z = d * acc[i].z; r.w = d * acc[i].w;
            *(float4*)&buf1[ii * 132 + fb] = r;
        }
    }
    __syncthreads();

    // ---- agg1 + tanh: buf1(g1) -> buf2(x2) ----
    agg_layer(t, buf1, buf2, colmask, dinv, bias1);
    __syncthreads();

    // ---- conv2: g2 = d .* (x2 @ W2), K=128, W2 staged 32-row panels into xl ----
    {
        float4 acc[8];
        #pragma unroll
        for (int i = 0; i < 8; ++i) acc[i] = make_float4(0.f, 0.f, 0.f, 0.f);
        for (int kb = 0; kb < 4; ++kb) {
            __syncthreads();   // previous panel fully consumed
            {
                const float4* src = (const float4*)(W2g + kb * 32 * NH);
                float4* dst = (float4*)xl;
                dst[t]       = src[t];
                dst[t + 512] = src[t + 512];
            }
            __syncthreads();
            #pragma unroll
            for (int ks = 0; ks < 8; ++ks) {
                const float4 w0 = *(const float4*)&xl[(4 * ks + 0) * NH + fb];
                const float4 w1 = *(const float4*)&xl[(4 * ks + 1) * NH + fb];
                const float4 w2 = *(const float4*)&xl[(4 * ks + 2) * NH + fb];
                const float4 w3 = *(const float4*)&xl[(4 * ks + 3) * NH + fb];
                #pragma unroll
                for (int i = 0; i < 8; ++i) {
                    const float4 xv = *(const float4*)&buf2[(ig * 8 + i) * 132 + (kb * 8 + ks) * 4];
                    FMA16(acc[i], xv, w0, w1, w2, w3)
                }
            }
        }
        __syncthreads();
        #pragma unroll
        for (int i = 0; i < 8; ++i) {
            const int ii = ig * 8 + i;
            const float d = dinv[ii];
            float4 r; r.x = d * acc[i].x; r.y = d * acc[i].y; r.z = d * acc[i].z; r.w = d * acc[i].w;
            *(float4*)&buf1[ii * 132 + fb] = r;
        }
    }
    __syncthreads();

    // ---- agg2 + tanh: buf1(g2) -> buf2(x3) ----
    agg_layer(t, buf1, buf2, colmask, dinv, bias2);
    __syncthreads();

    // ---- head: out[j] = x3[j] . wo + bout ----
    {
        const float* x3 = &buf2[i4 * 132 + p4 * 32];
        float s = 0.f;
        #pragma unroll
        for (int q = 0; q < 8; ++q) {
            const float4 v = *(const float4*)&x3[q * 4];
            const float4 w = *(const float4*)&wo[p4 * 32 + q * 4];
            s = fmaf(v.x, w.x, s); s = fmaf(v.y, w.y, s);
            s = fmaf(v.z, w.z, s); s = fmaf(v.w, w.w, s);
        }
        s += __shfl_xor(s, 1, 64);
        s += __shfl_xor(s, 2, 64);
        if (p4 == 0) outg[b * NA + i4] = s + bog[0];
    }
}

extern "C" void kernel_launch(void* const* d_in, const int* in_sizes, int n_in,
                              void* d_out, int out_size, void* d_ws, size_t ws_size,
                              hipStream_t stream) {
    const float* obs = (const float*)d_in[0];
    const float* W1  = (const float*)d_in[1];
    const float* b1  = (const float*)d_in[2];
    const float* W2  = (const float*)d_in[3];
    const float* b2  = (const float*)d_in[4];
    const float* Wo  = (const float*)d_in[5];
    const float* bo  = (const float*)d_in[6];
    float* out = (float*)d_out;
    const int B = in_sizes[0] / (NA * ND);
    hipLaunchKernelGGL(gnn_fused, dim3(B), dim3(512), 0, stream,
                       obs, W1, b1, W2, b2, Wo, bo, out);
}

// Round 2
// 48.178 us; speedup vs baseline: 2.4084x; 2.4084x over previous
//
#include <hip/hip_runtime.h>

#define NA 128   // agents per batch
#define NKN 16   // neighbours

typedef _Float16 f16;
typedef _Float16 f16x8 __attribute__((ext_vector_type(8)));
typedef float    f32x16 __attribute__((ext_vector_type(16)));

#define MFMA __builtin_amdgcn_mfma_f32_32x32x16_f16
// XOR swizzle for [row][256B] f16 matrices: spreads 8 consecutive rows over 8 16B slots
#define SWZ(row, byteoff) ((byteoff) ^ (((row)&7)<<4))

__device__ __forceinline__ float tanh_fast(float x){
    // (e^2x-1)/(e^2x+1), clamped; rel err ~1e-6, well under threshold
    float xc = fminf(fmaxf(x, -9.f), 9.f);
    float e  = __expf(2.f*xc);
    return (e - 1.f) / (e + 1.f);
}

__device__ __forceinline__ f16x8 bits_to_f16(unsigned int byte){
    f16x8 r;
    #pragma unroll
    for (int s = 0; s < 8; ++s) r[s] = ((byte >> s) & 1u) ? (f16)1.f : (f16)0.f;
    return r;
}

__device__ __forceinline__ unsigned int wsel(const uint4 c, int i){ // i is compile-time
    return i==0 ? c.x : i==1 ? c.y : i==2 ? c.z : c.w;
}

// Aggregation matmul: OUT[h_row][j_col] = sum_i IN[h][i] * M[i][j], M from colmask bits
// (diagonal included = self-loop). Epilogue: X = tanh(d_j*OUT + bias[h]) stored-T to matOut[j][h].
__device__ __forceinline__ void agg_mm(const unsigned char* matIn, unsigned char* matOut,
                                       const unsigned int (*cmask)[4], const float* dinv_s,
                                       const float* bias, int wv, int lane)
{
    const int lr = lane & 31, lg = lane >> 5;
    const int rb = wv & 3, ch = wv >> 2;
    f32x16 c0, c1;
    #pragma unroll
    for (int e = 0; e < 16; ++e) { c0[e] = 0.f; c1[e] = 0.f; }

    const int j0 = ch*64 + lr, j1 = j0 + 32;
    const uint4 cm0 = *(const uint4*)&cmask[j0][0];
    const uint4 cm1 = *(const uint4*)&cmask[j1][0];
    const int row = rb*32 + lr;   // h

    #pragma unroll
    for (int ks = 0; ks < 8; ++ks) {
        f16x8 af = *(const f16x8*)(matIn + row*256 + SWZ(row, ks*32 + lg*16));
        const unsigned int w0 = wsel(cm0, ks>>1);
        const unsigned int w1 = wsel(cm1, ks>>1);
        const int sh = (ks&1)*16 + lg*8;
        c0 = MFMA(af, bits_to_f16((w0 >> sh) & 0xFFu), c0, 0, 0, 0);
        c1 = MFMA(af, bits_to_f16((w1 >> sh) & 0xFFu), c1, 0, 0, 0);
    }
    #pragma unroll
    for (int ct = 0; ct < 2; ++ct) {
        const int j = ct ? j1 : j0;
        const float dj = dinv_s[j];
        #pragma unroll
        for (int q = 0; q < 4; ++q) {
            const int r0 = rb*32 + q*8 + lg*4;   // h quad
            const float4 bv = *(const float4*)&bias[r0];
            union { f16 h4[4]; unsigned long long u; } pk;
            if (ct == 0) {
                pk.h4[0] = (f16)tanh_fast(fmaf(dj, c0[q*4+0], bv.x));
                pk.h4[1] = (f16)tanh_fast(fmaf(dj, c0[q*4+1], bv.y));
                pk.h4[2] = (f16)tanh_fast(fmaf(dj, c0[q*4+2], bv.z));
                pk.h4[3] = (f16)tanh_fast(fmaf(dj, c0[q*4+3], bv.w));
            } else {
                pk.h4[0] = (f16)tanh_fast(fmaf(dj, c1[q*4+0], bv.x));
                pk.h4[1] = (f16)tanh_fast(fmaf(dj, c1[q*4+1], bv.y));
                pk.h4[2] = (f16)tanh_fast(fmaf(dj, c1[q*4+2], bv.z));
                pk.h4[3] = (f16)tanh_fast(fmaf(dj, c1[q*4+3], bv.w));
            }
            *(unsigned long long*)(matOut + j*256 + SWZ(j, r0*2)) = pk.u;
        }
    }
}

__global__ __launch_bounds__(512, 4) void gnn_fused(
    const float* __restrict__ obs,
    const float* __restrict__ W1g, const float* __restrict__ b1g,
    const float* __restrict__ W2g, const float* __restrict__ b2g,
    const float* __restrict__ Wog, const float* __restrict__ bog,
    float* __restrict__ outg)
{
    __shared__ __align__(16) unsigned char mat0[32768]; // W1 f32 staging -> G1[h][i] -> W2 panel f32 -> G2[h2][j]
    __shared__ __align__(16) unsigned char mat1[32768]; // obs f32 staging -> X2[j][h] -> X3[j][h2]
    __shared__ float posx[NA], posy[NA], dinv_s[NA], b1s[NA], b2s[NA], wos[NA];
    __shared__ unsigned int cmask[NA][4];   // bit i of cmask[j]: edge i->j (incl. diagonal)

    const int t = threadIdx.x;
    const int b = blockIdx.x;
    const int wv = t >> 6, lane = t & 63;
    const int lr = lane & 31, lg = lane >> 5;

    float* Xs  = (float*)mat1;   // [128][36] padded f32
    float* W1s = (float*)mat0;   // [32][132] padded f32

    // ---- phase 0: stage obs + W1 (f32, padded) + params; init colmask with diagonal ----
    {
        const float4* ob = (const float4*)(obs + (size_t)b * NA * 32);
        #pragma unroll
        for (int rep = 0; rep < 2; ++rep) {
            int idx = rep*512 + t;            // 1024 float4 = [128][32]
            int i = idx >> 3, seg = idx & 7;
            *(float4*)&Xs[i*36 + seg*4] = ob[idx];
        }
        #pragma unroll
        for (int rep = 0; rep < 2; ++rep) {
            int idx = rep*512 + t;            // 1024 float4 = [32][128]
            int d = idx >> 5, h4 = idx & 31;
            *(float4*)&W1s[d*132 + h4*4] = ((const float4*)W1g)[idx];
        }
        if (t < NA) { b1s[t] = b1g[t]; b2s[t] = b2g[t]; wos[t] = Wog[t]; }
        { int j = t >> 2, w = t & 3; cmask[j][w] = (w == (j>>5)) ? (1u << (j&31)) : 0u; }
    }
    __syncthreads();
    if (t < NA) { posx[t] = Xs[t*36]; posy[t] = Xs[t*36 + 1]; }
    __syncthreads();

    // ---- phase 1: kNN in registers (bit-exact distances, exact top-k tie-break) ----
    {
        const int ia = t >> 2, p4 = t & 3;
        float dd[32];
        const float xi = posx[ia], yi = posy[ia];
        #pragma unroll
        for (int jj = 0; jj < 32; ++jj) {
            const int j = p4*32 + jj;
            const float dx = __fsub_rn(xi, posx[j]);
            const float dy = __fsub_rn(yi, posy[j]);
            const float d  = __fsqrt_rn(__fadd_rn(__fmul_rn(dx,dx), __fmul_rn(dy,dy)));
            dd[jj] = (j == ia) ? __builtin_inff() : d;   // exclude self
        }
        for (int pass = 0; pass < NKN; ++pass) {
            float bd = dd[0]; int bj = p4*32;
            #pragma unroll
            for (int jj = 1; jj < 32; ++jj) {            // strict < : earliest index wins ties
                const bool lt = dd[jj] < bd;
                bd = lt ? dd[jj] : bd;
                bj = lt ? p4*32 + jj : bj;
            }
            #pragma unroll
            for (int m = 1; m <= 2; m <<= 1) {
                const float od = __shfl_xor(bd, m, 64);
                const int   oj = __shfl_xor(bj, m, 64);
                const bool take = (od < bd) || ((od == bd) && (oj < bj));
                bd = take ? od : bd;
                bj = take ? oj : bj;
            }
            if (p4 == 0) atomicOr(&cmask[bj][ia>>5], 1u << (ia & 31));
            const int lj = bj - p4*32;
            #pragma unroll
            for (int jj = 0; jj < 32; ++jj) dd[jj] = (jj == lj) ? __builtin_inff() : dd[jj];
        }
    }
    __syncthreads();
    if (t < NA) {
        int pc = __popc(cmask[t][0]) + __popc(cmask[t][1]) + __popc(cmask[t][2]) + __popc(cmask[t][3]);
        dinv_s[t] = rsqrtf((float)pc);   // popcount includes diagonal = 1 + indeg
    }
    __syncthreads();

    // ---- phase 2: conv1 (OUT rows=node, cols=h; A=X f32-staged, B=W1^T gathered) ----
    {
        f32x16 c0, c1;
        #pragma unroll
        for (int e = 0; e < 16; ++e) { c0[e] = 0.f; c1[e] = 0.f; }
        const int rb = wv & 3, ch = wv >> 2;
        const int row = rb*32 + lr;     // node
        #pragma unroll
        for (int ks = 0; ks < 2; ++ks) {
            f16x8 af;
            const float* ap = Xs + row*36 + ks*16 + lg*8;
            #pragma unroll
            for (int s = 0; s < 8; ++s) af[s] = (f16)ap[s];
            #pragma unroll
            for (int ct = 0; ct < 2; ++ct) {
                const int h = ch*64 + ct*32 + lr;
                f16x8 bf;
                #pragma unroll
                for (int s = 0; s < 8; ++s) bf[s] = (f16)W1s[(ks*16 + lg*8 + s)*132 + h];
                if (ct == 0) c0 = MFMA(af, bf, c0, 0, 0, 0);
                else         c1 = MFMA(af, bf, c1, 0, 0, 0);
            }
        }
        __syncthreads();   // all waves done reading mat0/mat1 before G1 overwrites mat0
        #pragma unroll
        for (int ct = 0; ct < 2; ++ct) {
            const int h = ch*64 + ct*32 + lr;
            #pragma unroll
            for (int q = 0; q < 4; ++q) {
                const int r0 = rb*32 + q*8 + lg*4;   // node quad
                const float4 dv = *(const float4*)&dinv_s[r0];
                union { f16 h4[4]; unsigned long long u; } pk;
                if (ct == 0) {
                    pk.h4[0] = (f16)(c0[q*4+0]*dv.x); pk.h4[1] = (f16)(c0[q*4+1]*dv.y);
                    pk.h4[2] = (f16)(c0[q*4+2]*dv.z); pk.h4[3] = (f16)(c0[q*4+3]*dv.w);
                } else {
                    pk.h4[0] = (f16)(c1[q*4+0]*dv.x); pk.h4[1] = (f16)(c1[q*4+1]*dv.y);
                    pk.h4[2] = (f16)(c1[q*4+2]*dv.z); pk.h4[3] = (f16)(c1[q*4+3]*dv.w);
                }
                *(unsigned long long*)(mat0 + h*256 + SWZ(h, r0*2)) = pk.u;  // G1[h][i]
            }
        }
    }
    __syncthreads();

    // ---- phase 3: agg1 -> X2[j][h] in mat1 ----
    agg_mm(mat0, mat1, cmask, dinv_s, b1s, wv, lane);
    __syncthreads();

    // ---- phase 4: conv2 in two col-halves; W2 panel f32-staged in mat0 ----
    {
        f32x16 accA, accB;
        #pragma unroll
        for (int e = 0; e < 16; ++e) { accA[e] = 0.f; accB[e] = 0.f; }
        const int rb = wv & 3, ct2 = wv >> 2;      // tile: rows j = rb*32.., cols h2 = ct2*32 (+half*64)
        float* Ws = (float*)mat0;                  // [128][64] f32 panel
        #pragma unroll
        for (int half = 0; half < 2; ++half) {
            #pragma unroll
            for (int rep = 0; rep < 4; ++rep) {
                int idx = rep*2048 + t*4;          // [k][h2] linear
                int k = idx >> 6, h2 = idx & 63;
                *(float4*)&Ws[idx] = *(const float4*)&W2g[k*128 + half*64 + h2];
            }
            __syncthreads();
            const int row = rb*32 + lr;            // j
            #pragma unroll
            for (int ks = 0; ks < 8; ++ks) {
                f16x8 af = *(const f16x8*)(mat1 + row*256 + SWZ(row, ks*32 + lg*16));
                const int h2c = ct2*32 + lr;
                f16x8 bf;
                const float* wp = Ws + (ks*16 + lg*8)*64 + h2c;
                #pragma unroll
                for (int s = 0; s < 8; ++s) bf[s] = (f16)wp[s*64];
                if (half == 0) accA = MFMA(af, bf, accA, 0, 0, 0);
                else           accB = MFMA(af, bf, accB, 0, 0, 0);
            }
            __syncthreads();   // panel fully consumed before reuse/overwrite
        }
        // epilogue: G2[h2][j] = d_j * H2, over mat0
        #pragma unroll
        for (int half = 0; half < 2; ++half) {
            const int h2 = half*64 + ct2*32 + lr;
            #pragma unroll
            for (int q = 0; q < 4; ++q) {
                const int r0 = rb*32 + q*8 + lg*4;   // j quad
                const float4 dv = *(const float4*)&dinv_s[r0];
                union { f16 h4[4]; unsigned long long u; } pk;
                if (half == 0) {
                    pk.h4[0] = (f16)(accA[q*4+0]*dv.x); pk.h4[1] = (f16)(accA[q*4+1]*dv.y);
                    pk.h4[2] = (f16)(accA[q*4+2]*dv.z); pk.h4[3] = (f16)(accA[q*4+3]*dv.w);
                } else {
                    pk.h4[0] = (f16)(accB[q*4+0]*dv.x); pk.h4[1] = (f16)(accB[q*4+1]*dv.y);
                    pk.h4[2] = (f16)(accB[q*4+2]*dv.z); pk.h4[3] = (f16)(accB[q*4+3]*dv.w);
                }
                *(unsigned long long*)(mat0 + h2*256 + SWZ(h2, r0*2)) = pk.u;
            }
        }
    }
    __syncthreads();

    // ---- phase 5: agg2 -> X3[j][h2] in mat1 ----
    agg_mm(mat0, mat1, cmask, dinv_s, b2s, wv, lane);
    __syncthreads();

    // ---- phase 6: head out[j] = X3[j] . wo + bout ----
    {
        const int ia = t >> 2, p4 = t & 3;
        float s = 0.f;
        #pragma unroll
        for (int u = 0; u < 4; ++u) {
            f16x8 v = *(const f16x8*)(mat1 + ia*256 + SWZ(ia, p4*64 + u*16));
            const float4 w0 = *(const float4*)&wos[p4*32 + u*8];
            const float4 w1 = *(const float4*)&wos[p4*32 + u*8 + 4];
            s = fmaf((float)v[0], w0.x, s); s = fmaf((float)v[1], w0.y, s);
            s = fmaf((float)v[2], w0.z, s); s = fmaf((float)v[3], w0.w, s);
            s = fmaf((float)v[4], w1.x, s); s = fmaf((float)v[5], w1.y, s);
            s = fmaf((float)v[6], w1.z, s); s = fmaf((float)v[7], w1.w, s);
        }
        s += __shfl_xor(s, 1, 64);
        s += __shfl_xor(s, 2, 64);
        if (p4 == 0) outg[b*NA + ia] = s + bog[0];
    }
}

extern "C" void kernel_launch(void* const* d_in, const int* in_sizes, int n_in,
                              void* d_out, int out_size, void* d_ws, size_t ws_size,
                              hipStream_t stream) {
    const float* obs = (const float*)d_in[0];
    const float* W1  = (const float*)d_in[1];
    const float* b1  = (const float*)d_in[2];
    const float* W2  = (const float*)d_in[3];
    const float* b2  = (const float*)d_in[4];
    const float* Wo  = (const float*)d_in[5];
    const float* bo  = (const float*)d_in[6];
    float* out = (float*)d_out;
    const int B = in_sizes[0] / (NA * 32);
    hipLaunchKernelGGL(gnn_fused, dim3(B), dim3(512), 0, stream,
                       obs, W1, b1, W2, b2, Wo, bo, out);
}

// Round 4
// 43.324 us; speedup vs baseline: 2.6783x; 1.1120x over previous
//
#include <hip/hip_runtime.h>

#define NA 128   // agents per batch
#define NKN 16   // neighbours

typedef _Float16 f16;
typedef __fp16   h16x2 __attribute__((ext_vector_type(2)));   // cvt_pkrtz result type
typedef _Float16 f16x8 __attribute__((ext_vector_type(8)));
typedef float    f32x16 __attribute__((ext_vector_type(16)));

#define MFMA __builtin_amdgcn_mfma_f32_32x32x16_f16
// 256B-row f16 matrices: XOR row bits into the 16B-slot index -> 16 slots, 2-way (free)
#define SWZ16(row, byteoff) ((byteoff) ^ (((row)&15)<<4))
// 64B-row f16 matrices (X, W1T): 4 slots
#define SWZ4(row, byteoff)  ((byteoff) ^ (((row)&3)<<4))

__device__ __forceinline__ float tanh_fast(float x){
    // 1 - 2/(e^{2x}+1); raw v_rcp (1e-5 rel) is far below f16 storage rounding.
    float e = __expf(2.f * x);
    return 1.f - 2.f * __builtin_amdgcn_rcpf(e + 1.f);
}

__device__ __forceinline__ unsigned int wsel(const uint4 c, int i){ // i compile-time
    return i==0 ? c.x : i==1 ? c.y : i==2 ? c.z : c.w;
}

// OUT[h][j] = sum_i IN[h][i]*M[i][j] (M incl. diagonal); X = tanh(d_j*OUT + bias[h]) stored-T.
__device__ __forceinline__ void agg_mm(const unsigned char* matIn, unsigned char* matOut,
                                       const unsigned int (*cmask)[4], const float* dinv_s,
                                       const float* bias, const unsigned long long* lut,
                                       int wv, int lane)
{
    const int lr = lane & 31, lg = lane >> 5;
    const int rb = wv & 3, ch = wv >> 2;
    f32x16 c0, c1;
    #pragma unroll
    for (int e = 0; e < 16; ++e) { c0[e] = 0.f; c1[e] = 0.f; }

    const int j0 = ch*64 + lr, j1 = j0 + 32;
    const uint4 cm0 = *(const uint4*)&cmask[j0][0];
    const uint4 cm1 = *(const uint4*)&cmask[j1][0];
    const int row = rb*32 + lr;   // h

    #pragma unroll
    for (int ks = 0; ks < 8; ++ks) {
        f16x8 af = *(const f16x8*)(matIn + row*256 + SWZ16(row, ks*32 + lg*16));
        const int sh = (ks&1)*16 + lg*8;
        const unsigned int b0 = (wsel(cm0, ks>>1) >> sh) & 0xFFu;
        const unsigned int b1 = (wsel(cm1, ks>>1) >> sh) & 0xFFu;
        union { f16x8 v; unsigned long long u[2]; } B0, B1;
        B0.u[0] = lut[b0 & 15u]; B0.u[1] = lut[b0 >> 4];
        B1.u[0] = lut[b1 & 15u]; B1.u[1] = lut[b1 >> 4];
        c0 = MFMA(af, B0.v, c0, 0, 0, 0);
        c1 = MFMA(af, B1.v, c1, 0, 0, 0);
    }
    #pragma unroll
    for (int ct = 0; ct < 2; ++ct) {
        const int j = ct ? j1 : j0;
        const float dj = dinv_s[j];
        #pragma unroll
        for (int q = 0; q < 4; ++q) {
            const int r0 = rb*32 + q*8 + lg*4;   // h quad
            const float4 bv = *(const float4*)&bias[r0];
            float v0, v1, v2, v3;
            if (ct == 0) {
                v0 = tanh_fast(fmaf(dj, c0[q*4+0], bv.x));
                v1 = tanh_fast(fmaf(dj, c0[q*4+1], bv.y));
                v2 = tanh_fast(fmaf(dj, c0[q*4+2], bv.z));
                v3 = tanh_fast(fmaf(dj, c0[q*4+3], bv.w));
            } else {
                v0 = tanh_fast(fmaf(dj, c1[q*4+0], bv.x));
                v1 = tanh_fast(fmaf(dj, c1[q*4+1], bv.y));
                v2 = tanh_fast(fmaf(dj, c1[q*4+2], bv.z));
                v3 = tanh_fast(fmaf(dj, c1[q*4+3], bv.w));
            }
            union { h16x2 h[2]; unsigned long long u; } pk;
            pk.h[0] = __builtin_amdgcn_cvt_pkrtz(v0, v1);
            pk.h[1] = __builtin_amdgcn_cvt_pkrtz(v2, v3);
            *(unsigned long long*)(matOut + j*256 + SWZ16(j, r0*2)) = pk.u;
        }
    }
}

// prep: pre-transposed + pre-swizzled f16 images of W1^T [128][32] and W2^T [128][128]
__global__ __launch_bounds__(512, 1) void prep(const float* __restrict__ W1g,
                                               const float* __restrict__ W2g,
                                               unsigned char* __restrict__ ws)
{
    const int m = blockIdx.x * 512 + threadIdx.x;   // grid 5 -> 2560 tiles
    if (m < 2048) {                                  // W2T tiles: 128 h2 x 16 k-groups
        const int h2 = m & 127, g = m >> 7;
        f16x8 v;
        #pragma unroll
        for (int s = 0; s < 8; ++s) v[s] = (f16)W2g[(g*8 + s)*128 + h2];
        *(f16x8*)(ws + 8192 + h2*256 + SWZ16(h2, g*16)) = v;
    } else {                                         // W1T tiles: 128 h x 4 k-groups
        const int m2 = m - 2048;
        const int h = m2 & 127, g = m2 >> 7;
        f16x8 v;
        #pragma unroll
        for (int s = 0; s < 8; ++s) v[s] = (f16)W1g[(g*8 + s)*128 + h];
        *(f16x8*)(ws + h*64 + SWZ4(h, g*16)) = v;
    }
}

__global__ __launch_bounds__(512, 4) void gnn_fused(
    const float* __restrict__ obs,
    const unsigned char* __restrict__ ws,     // prep images
    const float* __restrict__ b1g, const float* __restrict__ b2g,
    const float* __restrict__ Wog, const float* __restrict__ bog,
    float* __restrict__ outg)
{
    __shared__ __align__(16) unsigned char mat0[32768]; // W1T(8K) -> G1 -> W2T -> X3
    __shared__ __align__(16) unsigned char mat1[32768]; // Xf16(8K) -> X2 -> G2
    __shared__ float posx[NA], posy[NA], dinv_s[NA], b1s[NA], b2s[NA], wos[NA];
    __shared__ unsigned int cmask[NA][4];
    __shared__ unsigned long long lut16[16];

    const int t = threadIdx.x;
    const int b = blockIdx.x;
    const int wv = t >> 6, lane = t & 63;
    const int lr = lane & 31, lg = lane >> 5;

    // ---- phase 0: stage obs->Xf16 (+pos f32), W1T image, params, cmask diag, LUT ----
    {
        const float4* ob = (const float4*)(obs + (size_t)b * NA * 32);
        #pragma unroll
        for (int rep = 0; rep < 2; ++rep) {
            const int idx = rep*512 + t;         // 1024 float4 = [128 i][8 seg]
            const int i = idx >> 3, seg = idx & 7;
            const float4 v = ob[idx];
            if (seg == 0) { posx[i] = v.x; posy[i] = v.y; }
            union { h16x2 h[2]; unsigned long long u; } pk;
            pk.h[0] = __builtin_amdgcn_cvt_pkrtz(v.x, v.y);
            pk.h[1] = __builtin_amdgcn_cvt_pkrtz(v.z, v.w);
            *(unsigned long long*)(mat1 + i*64 + SWZ4(i, seg*8)) = pk.u;
        }
        *(f16x8*)(mat0 + t*16) = *(const f16x8*)(ws + t*16);   // W1T 8KB verbatim
        if (t < NA) { b1s[t] = b1g[t]; b2s[t] = b2g[t]; wos[t] = Wog[t]; }
        { const int j = t >> 2, w = t & 3; cmask[j][w] = (w == (j>>5)) ? (1u << (j&31)) : 0u; }
        if (t < 16) {
            unsigned long long e = 0ull;
            #pragma unroll
            for (int s = 0; s < 4; ++s)
                if ((t >> s) & 1) e |= 0x3C00ull << (16*s);   // f16 1.0
            lut16[t] = e;
        }
    }
    __syncthreads();

    // ---- phase 1: kNN in registers (bit-exact distances, exact index tie-break) ----
    {
        const int ia = t >> 2, p4 = t & 3;
        float dd[32];
        const float xi = posx[ia], yi = posy[ia];
        #pragma unroll
        for (int jj = 0; jj < 32; ++jj) {
            const int j = p4*32 + jj;
            const float dx = __fsub_rn(xi, posx[j]);
            const float dy = __fsub_rn(yi, posy[j]);
            const float d  = __fsqrt_rn(__fadd_rn(__fmul_rn(dx,dx), __fmul_rn(dy,dy)));
            dd[jj] = (j == ia) ? __builtin_inff() : d;
        }
        for (int pass = 0; pass < NKN; ++pass) {
            float bd = dd[0]; int bj = p4*32;
            #pragma unroll
            for (int jj = 1; jj < 32; ++jj) {    // strict <: earliest index wins ties
                const bool lt = dd[jj] < bd;
                bd = lt ? dd[jj] : bd;
                bj = lt ? p4*32 + jj : bj;
            }
            // d>=0 (or +inf) -> f32 bits monotone; key compare = lexicographic (d, idx)
            unsigned long long key = ((unsigned long long)__float_as_uint(bd) << 32) | (unsigned)bj;
            #pragma unroll
            for (int m = 1; m <= 2; m <<= 1) {
                const unsigned long long ok = __shfl_xor(key, m, 64);
                key = (ok < key) ? ok : key;
            }
            bj = (int)(key & 0xFFFFFFFFull);
            if ((bj >> 5) == p4) {               // owner invalidates its local element
                const int lj = bj & 31;
                #pragma unroll
                for (int jj = 0; jj < 32; ++jj) dd[jj] = (jj == lj) ? __builtin_inff() : dd[jj];
            }
            if (p4 == 0) atomicOr(&cmask[bj][ia>>5], 1u << (ia & 31));
        }
    }
    __syncthreads();
    if (t < NA)
        dinv_s[t] = rsqrtf((float)(__popc(cmask[t][0]) + __popc(cmask[t][1]) +
                                   __popc(cmask[t][2]) + __popc(cmask[t][3])));
    __syncthreads();

    // ---- phase 2: conv1  G1[h][i] = d_i*(X@W1)[i][h]  (A=Xf16, B=W1T, 16B frags) ----
    {
        f32x16 c0, c1;
        #pragma unroll
        for (int e = 0; e < 16; ++e) { c0[e] = 0.f; c1[e] = 0.f; }
        const int rb = wv & 3, ch = wv >> 2;
        const int row = rb*32 + lr;              // node i
        #pragma unroll
        for (int ks = 0; ks < 2; ++ks) {
            const f16x8 af = *(const f16x8*)(mat1 + row*64 + SWZ4(row, ks*32 + lg*16));
            #pragma unroll
            for (int ct = 0; ct < 2; ++ct) {
                const int h = ch*64 + ct*32 + lr;
                const f16x8 bf = *(const f16x8*)(mat0 + h*64 + SWZ4(h, ks*32 + lg*16));
                if (ct == 0) c0 = MFMA(af, bf, c0, 0, 0, 0);
                else         c1 = MFMA(af, bf, c1, 0, 0, 0);
            }
        }
        __syncthreads();   // all W1T/X reads done before G1 overwrites mat0
        #pragma unroll
        for (int ct = 0; ct < 2; ++ct) {
            const int h = ch*64 + ct*32 + lr;
            #pragma unroll
            for (int q = 0; q < 4; ++q) {
                const int r0 = rb*32 + q*8 + lg*4;   // node quad
                const float4 dv = *(const float4*)&dinv_s[r0];
                union { h16x2 hh[2]; unsigned long long u; } pk;
                if (ct == 0) {
                    pk.hh[0] = __builtin_amdgcn_cvt_pkrtz(c0[q*4+0]*dv.x, c0[q*4+1]*dv.y);
                    pk.hh[1] = __builtin_amdgcn_cvt_pkrtz(c0[q*4+2]*dv.z, c0[q*4+3]*dv.w);
                } else {
                    pk.hh[0] = __builtin_amdgcn_cvt_pkrtz(c1[q*4+0]*dv.x, c1[q*4+1]*dv.y);
                    pk.hh[1] = __builtin_amdgcn_cvt_pkrtz(c1[q*4+2]*dv.z, c1[q*4+3]*dv.w);
                }
                *(unsigned long long*)(mat0 + h*256 + SWZ16(h, r0*2)) = pk.u;
            }
        }
    }
    __syncthreads();

    // ---- phase 3: agg1 -> X2[j][h] in mat1 ----
    agg_mm(mat0, mat1, cmask, dinv_s, b1s, lut16, wv, lane);
    __syncthreads();

    // ---- phase 4: stage W2T image (verbatim), then conv2 -> G2[h2][j] ----
    {
        #pragma unroll
        for (int rep = 0; rep < 4; ++rep) {
            const int idx = rep*512 + t;
            *(f16x8*)(mat0 + idx*16) = *(const f16x8*)(ws + 8192 + idx*16);
        }
    }
    __syncthreads();
    {
        f32x16 c0, c1;
        #pragma unroll
        for (int e = 0; e < 16; ++e) { c0[e] = 0.f; c1[e] = 0.f; }
        const int rb = wv & 3, ch = wv >> 2;
        const int row = rb*32 + lr;              // j
        #pragma unroll
        for (int ks = 0; ks < 8; ++ks) {
            const f16x8 af = *(const f16x8*)(mat1 + row*256 + SWZ16(row, ks*32 + lg*16));
            #pragma unroll
            for (int ct = 0; ct < 2; ++ct) {
                const int h2 = ch*64 + ct*32 + lr;
                const f16x8 bf = *(const f16x8*)(mat0 + h2*256 + SWZ16(h2, ks*32 + lg*16));
                if (ct == 0) c0 = MFMA(af, bf, c0, 0, 0, 0);
                else         c1 = MFMA(af, bf, c1, 0, 0, 0);
            }
        }
        __syncthreads();   // X2/W2T reads done before G2 overwrites mat1
        #pragma unroll
        for (int ct = 0; ct < 2; ++ct) {
            const int h2 = ch*64 + ct*32 + lr;
            #pragma unroll
            for (int q = 0; q < 4; ++q) {
                const int r0 = rb*32 + q*8 + lg*4;   // j quad
                const float4 dv = *(const float4*)&dinv_s[r0];
                union { h16x2 hh[2]; unsigned long long u; } pk;
                if (ct == 0) {
                    pk.hh[0] = __builtin_amdgcn_cvt_pkrtz(c0[q*4+0]*dv.x, c0[q*4+1]*dv.y);
                    pk.hh[1] = __builtin_amdgcn_cvt_pkrtz(c0[q*4+2]*dv.z, c0[q*4+3]*dv.w);
                } else {
                    pk.hh[0] = __builtin_amdgcn_cvt_pkrtz(c1[q*4+0]*dv.x, c1[q*4+1]*dv.y);
                    pk.hh[1] = __builtin_amdgcn_cvt_pkrtz(c1[q*4+2]*dv.z, c1[q*4+3]*dv.w);
                }
                *(unsigned long long*)(mat1 + h2*256 + SWZ16(h2, r0*2)) = pk.u;
            }
        }
    }
    __syncthreads();

    // ---- phase 5: agg2 -> X3[j][h2] in mat0 ----
    agg_mm(mat1, mat0, cmask, dinv_s, b2s, lut16, wv, lane);
    __syncthreads();

    // ---- phase 6: head out[j] = X3[j].wo + bout ----
    {
        const int ia = t >> 2, p4 = t & 3;
        float s = 0.f;
        #pragma unroll
        for (int u = 0; u < 4; ++u) {
            const f16x8 v = *(const f16x8*)(mat0 + ia*256 + SWZ16(ia, p4*64 + u*16));
            const float4 w0 = *(const float4*)&wos[p4*32 + u*8];
            const float4 w1 = *(const float4*)&wos[p4*32 + u*8 + 4];
            s = fmaf((float)v[0], w0.x, s); s = fmaf((float)v[1], w0.y, s);
            s = fmaf((float)v[2], w0.z, s); s = fmaf((float)v[3], w0.w, s);
            s = fmaf((float)v[4], w1.x, s); s = fmaf((float)v[5], w1.y, s);
            s = fmaf((float)v[6], w1.z, s); s = fmaf((float)v[7], w1.w, s);
        }
        s += __shfl_xor(s, 1, 64);
        s += __shfl_xor(s, 2, 64);
        if (p4 == 0) outg[b*NA + ia] = s + bog[0];
    }
}

extern "C" void kernel_launch(void* const* d_in, const int* in_sizes, int n_in,
                              void* d_out, int out_size, void* d_ws, size_t ws_size,
                              hipStream_t stream) {
    const float* obs = (const float*)d_in[0];
    const float* W1  = (const float*)d_in[1];
    const float* b1  = (const float*)d_in[2];
    const float* W2  = (const float*)d_in[3];
    const float* b2  = (const float*)d_in[4];
    const float* Wo  = (const float*)d_in[5];
    const float* bo  = (const float*)d_in[6];
    float* out = (float*)d_out;
    const int B = in_sizes[0] / (NA * 32);
    unsigned char* ws = (unsigned char*)d_ws;   // needs 40 KB: W1T(8K) + W2T(32K)
    hipLaunchKernelGGL(prep, dim3(5), dim3(512), 0, stream, W1, W2, ws);
    hipLaunchKernelGGL(gnn_fused, dim3(B), dim3(512), 0, stream,
                       obs, ws, b1, b2, Wo, bo, out);
}